// Round 1
// baseline (249.688 us; speedup 1.0000x reference)
//
#include <hip/hip_runtime.h>
#include <hip/hip_bf16.h>

#define NS     32768   // samples per row
#define NROWS  2048
#define NF     255     // window length (odd!)
#define HOP    127
#define NW     257     // number of windows
#define NB     128     // output bins = rfft(255) bins
#define MTILES 17      // ceil(257/16) -> 272 padded windows
#define KSTEPS 8       // K = 256 (255 + 1 zero pad) / 32

typedef _Float16 f16;
typedef __attribute__((ext_vector_type(8))) _Float16 f16x8;
typedef __attribute__((ext_vector_type(4))) float f32x4;

// One workgroup (4 waves, 256 thr) per row.
// Wave w owns frequency-component columns [w*64, w*64+64): cols 0..127 = cos(f),
// cols 128..255 = sin(f-128). S[row,f] = (sum_w C_cos^2 + C_sin^2)/257.
__global__ __launch_bounds__(256, 2)
void psd_mfma_kernel(const float* __restrict__ X, float* __restrict__ out) {
    const int row  = blockIdx.x;
    const int tid  = threadIdx.x;
    const int lane = tid & 63;
    const int wave = tid >> 6;
    const int r16  = lane & 15;   // A-row / D-col within 16x16 tile
    const int kg   = lane >> 4;   // k-group (8 consecutive k per group)

    __shared__ alignas(16) f16 atile[2][16 * 256];  // 2 x 8 KB, XOR-swizzled rows
    __shared__ float scol[256];

    const float* __restrict__ xrow = X + (size_t)row * NS;

    const int sw16 = tid >> 4;          // staging: row within tile
    const int sk0  = (tid & 15) * 16;   // staging: k base (16 elems/thread)

    // ---- stage_load(tile 0): issue global loads early, hide under B-gen ----
    float vals[16];
    {
        const int base = sw16 * HOP + sk0;   // mtile 0
        #pragma unroll
        for (int i = 0; i < 16; ++i) {
            int idx = base + i; idx = idx < NS ? idx : NS - 1;  // clamp (safety)
            vals[i] = xrow[idx];
        }
    }

    // ---- generate DFT fragments (B operand) in registers: 32 frags = 128 VGPR ----
    // B[k, c]: lane holds c = wave*64 + nt*16 + r16, k = kk*32 + kg*8 + j.
    f16x8 bfrag[4][KSTEPS];
    {
        #pragma unroll
        for (int nt = 0; nt < 4; ++nt) {
            const int cc = wave * 64 + nt * 16 + r16;
            const int f  = cc & 127;
            const bool is_sin = cc >= 128;
            #pragma unroll
            for (int kk = 0; kk < KSTEPS; ++kk) {
                f16x8 v;
                #pragma unroll
                for (int j = 0; j < 8; ++j) {
                    const int k = kk * 32 + kg * 8 + j;
                    float val = 0.0f;                    // k = 255 zero pad
                    if (k < NF) {
                        const int m = (f * k) % NF;      // exact phase reduction
                        const float ang = (float)m * (6.28318530717958647692f / 255.0f);
                        val = is_sin ? __sinf(ang) : __cosf(ang);
                    }
                    v[j] = (f16)val;
                }
                bfrag[nt][kk] = v;
            }
        }
    }

    // ---- stage_write(tile 0) ----
    {
        const bool valid = (sw16 < NW);                  // always true for tile 0
        const uint sbase = (uint)(sw16 * 512 + sk0 * 2);
        const uint swz   = (uint)((sw16 & 7) << 4);
        char* wp = (char*)&atile[0][0];
        f16x8 h0, h1;
        #pragma unroll
        for (int i = 0; i < 8; ++i) h0[i] = valid ? (f16)vals[i]     : (f16)0.0f;
        #pragma unroll
        for (int i = 0; i < 8; ++i) h1[i] = valid ? (f16)vals[8 + i] : (f16)0.0f;
        *(f16x8*)(wp + (sbase ^ swz))        = h0;
        *(f16x8*)(wp + ((sbase + 16) ^ swz)) = h1;
    }

    float ssum[4] = {0.f, 0.f, 0.f, 0.f};

    for (int mt = 0; mt < MTILES; ++mt) {
        __syncthreads();   // staged tile (mt&1) visible to all waves

        // issue NEXT tile's global loads early (latency hides under MFMAs)
        const bool have_next = (mt + 1 < MTILES);
        bool nvalid = false;
        if (have_next) {
            const int w = (mt + 1) * 16 + sw16;
            nvalid = (w < NW);                 // zero-stage pad windows 257..271
            const int base = w * HOP + sk0;
            #pragma unroll
            for (int i = 0; i < 16; ++i) {
                int idx = base + i; idx = idx < NS ? idx : NS - 1;
                vals[i] = xrow[idx];
            }
        }

        // A fragments for current tile: one aligned ds_read_b128 each (swizzled)
        const char* ap = (const char*)&atile[mt & 1][0];
        const uint rbase = (uint)(r16 * 512 + kg * 16);
        const uint rswz  = (uint)((r16 & 7) << 4);
        f16x8 afrag[KSTEPS];
        #pragma unroll
        for (int kk = 0; kk < KSTEPS; ++kk) {
            afrag[kk] = *(const f16x8*)(ap + ((rbase + (uint)(kk * 64)) ^ rswz));
        }

        // 32 MFMAs: 4 independent acc chains interleave over 8 K-steps
        f32x4 acc0 = {0,0,0,0}, acc1 = {0,0,0,0}, acc2 = {0,0,0,0}, acc3 = {0,0,0,0};
        #pragma unroll
        for (int kk = 0; kk < KSTEPS; ++kk) {
            acc0 = __builtin_amdgcn_mfma_f32_16x16x32_f16(afrag[kk], bfrag[0][kk], acc0, 0, 0, 0);
            acc1 = __builtin_amdgcn_mfma_f32_16x16x32_f16(afrag[kk], bfrag[1][kk], acc1, 0, 0, 0);
            acc2 = __builtin_amdgcn_mfma_f32_16x16x32_f16(afrag[kk], bfrag[2][kk], acc2, 0, 0, 0);
            acc3 = __builtin_amdgcn_mfma_f32_16x16x32_f16(afrag[kk], bfrag[3][kk], acc3, 0, 0, 0);
        }
        // square-accumulate (zero-padded windows contribute exactly 0)
        #pragma unroll
        for (int r = 0; r < 4; ++r) {
            ssum[0] += acc0[r] * acc0[r];
            ssum[1] += acc1[r] * acc1[r];
            ssum[2] += acc2[r] * acc2[r];
            ssum[3] += acc3[r] * acc3[r];
        }

        // write next tile into the other LDS buffer (forces vmcnt wait here, after MFMAs)
        if (have_next) {
            const uint sbase = (uint)(sw16 * 512 + sk0 * 2);
            const uint swz   = (uint)((sw16 & 7) << 4);
            char* wp = (char*)&atile[(mt + 1) & 1][0];
            f16x8 h0, h1;
            #pragma unroll
            for (int i = 0; i < 8; ++i) h0[i] = nvalid ? (f16)vals[i]     : (f16)0.0f;
            #pragma unroll
            for (int i = 0; i < 8; ++i) h1[i] = nvalid ? (f16)vals[8 + i] : (f16)0.0f;
            *(f16x8*)(wp + (sbase ^ swz))        = h0;
            *(f16x8*)(wp + ((sbase + 16) ^ swz)) = h1;
        }
    }

    // ---- reduce over k-groups (D col = lane&15 is the verified mapping) ----
    #pragma unroll
    for (int nt = 0; nt < 4; ++nt) {
        float v = ssum[nt];
        v += __shfl_xor(v, 16, 64);
        v += __shfl_xor(v, 32, 64);
        if (kg == 0) scol[wave * 64 + nt * 16 + r16] = v;
    }
    __syncthreads();
    if (tid < NB) {
        out[(size_t)row * NB + tid] = (scol[tid] + scol[tid + NB]) * (1.0f / 257.0f);
    }
}

extern "C" void kernel_launch(void* const* d_in, const int* in_sizes, int n_in,
                              void* d_out, int out_size, void* d_ws, size_t ws_size,
                              hipStream_t stream) {
    const float* X = (const float*)d_in[0];
    float* out = (float*)d_out;
    (void)in_sizes; (void)n_in; (void)d_ws; (void)ws_size; (void)out_size;
    psd_mfma_kernel<<<dim3(NROWS), dim3(256), 0, stream>>>(X, out);
}

// Round 2
// 66.845 us; speedup vs baseline: 3.7353x; 3.7353x over previous
//
#include <hip/hip_runtime.h>
#include <hip/hip_bf16.h>

#define NS     32768
#define NROWS  2048
#define HOP    127
#define NW     257
#define NB     128
#define WTILE  16
#define NT     17            // ceil(257/16); tile 16 has 1 valid window
#define TWOPI_255 0.02463994236f   // 2*pi/255

typedef _Float16 f16;
typedef __attribute__((ext_vector_type(8))) _Float16 f16x8;
typedef __attribute__((ext_vector_type(4))) float f32x4;

__device__ inline f32x4 load4u(const float* p) {  // 4B-aligned 16B load
    f32x4 v;
    __builtin_memcpy(&v, p, 16);
    return v;
}

// One block (4 waves) per row. Wave cq owns components [cq*64, cq*64+64):
// comps 0..127 = cos(f), 128..255 = sin(f-128). K folded to 128 via
// y+[k] = x[k]+x[255-k] (cos part), y-[k] = x[k]-x[255-k] (sin part).
// S[f] = (sum_w Ccos^2 + Csin^2)/257.
__global__ __launch_bounds__(256, 4)
void psd_fold_kernel(const float* __restrict__ X, float* __restrict__ out) {
    const int row  = blockIdx.x;
    const int tid  = threadIdx.x;
    const int lane = tid & 63;
    const int cq   = tid >> 6;      // wave id
    const int r16  = lane & 15;
    const int kg   = lane >> 4;
    const int is_sin = cq >> 1;     // waves 2,3 -> sin half

    __shared__ alignas(16) f16 atile[2][WTILE * 256];  // [w][ y+ 0..127 | y- 128..255 ], swizzled
    __shared__ float scol[256];

    const float* __restrict__ xrow = X + (size_t)row * NS;

    const int sw  = tid >> 4;           // staging window 0..15
    const int sk0 = (tid & 15) * 8;     // staging k-octet base

    // ---- issue tile-0 loads early (hide under B-gen) ----
    f32x4 fva, fvb, rva, rvb;
    {
        const int b = sw * HOP;                       // tile 0 always valid
        fva = load4u(xrow + b + sk0);
        fvb = load4u(xrow + b + sk0 + 4);
        rva = load4u(xrow + b + 248 - sk0);
        rvb = load4u(xrow + b + 252 - sk0);
    }

    // ---- generate folded DFT basis: 64 VGPRs resident per wave ----
    f16x8 bfrag[4][4];
    #pragma unroll
    for (int nt = 0; nt < 4; ++nt) {
        const int comp = cq * 64 + nt * 16 + r16;
        const int f    = comp & 127;
        #pragma unroll
        for (int kk = 0; kk < 4; ++kk) {
            int m = (f * (kk * 32 + kg * 8)) % 255;   // one mod per frag
            f16x8 v;
            #pragma unroll
            for (int j = 0; j < 8; ++j) {
                const float ang = (float)m * TWOPI_255;
                const float s   = is_sin ? __sinf(ang) : __cosf(ang);
                v[j] = (f16)s;
                m += f; if (m >= 255) m -= 255;       // incremental phase
            }
            bfrag[nt][kk] = v;
        }
    }

    // ---- fold + write helper ----
    const f16x8 z8 = {(f16)0,(f16)0,(f16)0,(f16)0,(f16)0,(f16)0,(f16)0,(f16)0};
    auto fold_write = [&](int buf, bool valid, f32x4 fa, f32x4 fb, f32x4 ra, f32x4 rb) {
        float yp[8], ym[8];
        #pragma unroll
        for (int j = 0; j < 8; ++j) {
            const float fj = (j < 4) ? fa[j] : fb[j - 4];
            const int   pi = 7 - j;                     // partner x[b+255-(sk0+j)]
            const float rj = (pi < 4) ? ra[pi] : rb[pi - 4];
            yp[j] = fj + rj;
            ym[j] = fj - rj;
        }
        if (sk0 == 0) { yp[0] = fa[0]; ym[0] = 0.0f; }  // k=0 pairs with zero pad
        f16x8 h0, h1;
        #pragma unroll
        for (int j = 0; j < 8; ++j) { h0[j] = (f16)yp[j]; h1[j] = (f16)ym[j]; }
        if (!valid) { h0 = z8; h1 = z8; }
        char* wp = (char*)&atile[buf][0];
        const uint sb  = (uint)(sw * 512 + sk0 * 2);
        const uint swz = (uint)((sw & 7) << 4);
        *(f16x8*)(wp + (sb ^ swz))         = h0;        // y+ half
        *(f16x8*)(wp + ((sb + 256) ^ swz)) = h1;        // y- half
    };

    fold_write(0, true, fva, fvb, rva, rvb);
    __syncthreads();

    float ssum[4] = {0.f, 0.f, 0.f, 0.f};
    const uint rswz  = (uint)((r16 & 7) << 4);
    const uint rbase = (uint)(r16 * 512 + is_sin * 256 + kg * 16);

    for (int mt = 0; mt < NT; ++mt) {
        const int  cur       = mt & 1;
        const bool have_next = (mt + 1 < NT);
        bool nvalid = false;
        if (have_next) {                               // issue next-tile loads early
            const int w = (mt + 1) * WTILE + sw;
            nvalid = (w < NW);
            int b = w * HOP; if (b > NS - 256) b = NS - 256;   // clamp pad windows
            fva = load4u(xrow + b + sk0);
            fvb = load4u(xrow + b + sk0 + 4);
            rva = load4u(xrow + b + 248 - sk0);
            rvb = load4u(xrow + b + 252 - sk0);
        }

        const char* ap = (const char*)&atile[cur][0];
        f32x4 acc0 = {0,0,0,0}, acc1 = {0,0,0,0}, acc2 = {0,0,0,0}, acc3 = {0,0,0,0};
        #pragma unroll
        for (int kk = 0; kk < 4; ++kk) {
            const f16x8 af = *(const f16x8*)(ap + ((rbase + (uint)(kk * 64)) ^ rswz));
            acc0 = __builtin_amdgcn_mfma_f32_16x16x32_f16(af, bfrag[0][kk], acc0, 0, 0, 0);
            acc1 = __builtin_amdgcn_mfma_f32_16x16x32_f16(af, bfrag[1][kk], acc1, 0, 0, 0);
            acc2 = __builtin_amdgcn_mfma_f32_16x16x32_f16(af, bfrag[2][kk], acc2, 0, 0, 0);
            acc3 = __builtin_amdgcn_mfma_f32_16x16x32_f16(af, bfrag[3][kk], acc3, 0, 0, 0);
        }
        #pragma unroll
        for (int r = 0; r < 4; ++r) {
            ssum[0] += acc0[r] * acc0[r];
            ssum[1] += acc1[r] * acc1[r];
            ssum[2] += acc2[r] * acc2[r];
            ssum[3] += acc3[r] * acc3[r];
        }

        if (have_next) fold_write(cur ^ 1, nvalid, fva, fvb, rva, rvb);
        __syncthreads();   // single barrier: dbuf write/read ordering
    }

    // ---- reduce over k-groups; each comp owned by exactly one wave ----
    #pragma unroll
    for (int nt = 0; nt < 4; ++nt) {
        float v = ssum[nt];
        v += __shfl_xor(v, 16, 64);
        v += __shfl_xor(v, 32, 64);
        if (kg == 0) scol[cq * 64 + nt * 16 + r16] = v;
    }
    __syncthreads();
    if (tid < NB) {
        out[(size_t)row * NB + tid] = (scol[tid] + scol[tid + NB]) * (1.0f / 257.0f);
    }
}

extern "C" void kernel_launch(void* const* d_in, const int* in_sizes, int n_in,
                              void* d_out, int out_size, void* d_ws, size_t ws_size,
                              hipStream_t stream) {
    const float* X = (const float*)d_in[0];
    float* out = (float*)d_out;
    (void)in_sizes; (void)n_in; (void)d_ws; (void)ws_size; (void)out_size;
    psd_fold_kernel<<<dim3(NROWS), dim3(256), 0, stream>>>(X, out);
}